// Round 3
// baseline (504.075 us; speedup 1.0000x reference)
//
#include <hip/hip_runtime.h>

// ---------------- problem constants ----------------
constexpr int D0  = 11;
constexpr int Hh  = 200;
constexpr int Ww  = 176;
constexpr int HWC = Hh * Ww;        // 35200
constexpr int NV  = 16000;
constexpr int ND1 = 5;              // D after first stride-2 (VALID, k=3)
constexpr int ND2 = 2;
constexpr int CAPN = 32000;         // cap for n1 and n2 (each voxel -> <=2 windows)
constexpr float EPS = 1e-5f;

// pair-list capacities (worst case)
constexpr int CAP1P  = 432000;      // conv1 real pairs (stored twice -> 864000 entries)
constexpr int CAP34P = 864000;      // 27 * CAPN
constexpr int CAP2P  = 32000;
constexpr int CAP5P  = 64000;

// ctr[] layout (ints): 0:cnt1 1:cnt2 | 8..34:c1 | 40..42:c2 | 48..74:c34 | 80..82:c5
//                      88..114:cur1 | 120..122:cur2 | 128..154:cur34 | 160..162:cur5

// ---------------- wave-aggregated helpers ----------------
__device__ inline void wave_count(bool has, int* counter) {
    unsigned long long m = __ballot(has);
    int lane = threadIdx.x & 63;
    if (m && lane == __builtin_ctzll(m)) atomicAdd(counter, (int)__popcll(m));
}

__device__ inline int wave_append(bool has, int* counter) {
    unsigned long long m = __ballot(has);
    if (!m) return -1;
    int lane = threadIdx.x & 63;
    int leader = __builtin_ctzll(m);
    int base = 0;
    if (lane == leader) base = atomicAdd(counter, (int)__popcll(m));
    base = __shfl(base, leader);
    return has ? base + (int)__popcll(m & ((1ull << lane) - 1)) : -1;
}

// ---------------- setup 1: scatter coors + weight transposes ----------------
__global__ __launch_bounds__(256) void setup1_k(const int* __restrict__ coors,
    int* __restrict__ grid0,
    const float* __restrict__ w1, const float* __restrict__ w2,
    const float* __restrict__ w3, const float* __restrict__ w4,
    const float* __restrict__ w5,
    float* __restrict__ w1t, float* __restrict__ w2t, float* __restrict__ w3t,
    float* __restrict__ w4t, float* __restrict__ w5t) {
    int idx = blockIdx.x * 256 + threadIdx.x;
    int role = blockIdx.y;
    if (role == 0) {
        if (idx < NV) {
            int4 c = reinterpret_cast<const int4*>(coors)[idx];
            grid0[c.y * HWC + c.z * Ww + c.w] = idx;
        }
        return;
    }
    const float* src; float* dst; int I, K;
    switch (role) {
        case 1:  src = w1; dst = w1t; I = 128; K = 27; break;
        case 2:  src = w2; dst = w2t; I = 64;  K = 3;  break;
        case 3:  src = w3; dst = w3t; I = 64;  K = 27; break;
        case 4:  src = w4; dst = w4t; I = 64;  K = 27; break;
        default: src = w5; dst = w5t; I = 64;  K = 3;  break;
    }
    int tot = 64 * I * K;
    if (idx >= tot) return;
    int o = idx / (I * K), r = idx % (I * K), ii = r / K, k = r % K;
    dst[(k * I + ii) * 64 + o] = src[idx];   // wt[k][i][o]
}

// ---------------- setup 2: level-1 list, level-2 list, count conv1 pairs ----------------
__global__ __launch_bounds__(256) void setup2_k(const int* __restrict__ coors,
    const int* __restrict__ grid0, int* __restrict__ grid1,
    int* __restrict__ list1, int* __restrict__ list2, int* __restrict__ ctr) {
    int idx = blockIdx.x * 256 + threadIdx.x;
    int role = blockIdx.y;
    if (role == 0) {
        bool occ = false; int p = idx;
        if (p < ND1 * HWC) {
            int d1 = p / HWC, yx = p - d1 * HWC;
            int b = (2 * d1) * HWC + yx;
            occ = (grid0[b] >= 0) || (grid0[b + HWC] >= 0) || (grid0[b + 2 * HWC] >= 0);
        }
        int s = wave_append(occ, ctr + 0);
        if (occ) { grid1[p] = s; list1[s] = p; }
    } else if (role == 1) {
        bool occ = false; int p = idx;
        if (p < ND2 * HWC) {
            int d2 = p / HWC, yx = p - d2 * HWC;
            #pragma unroll
            for (int dd = 0; dd < 7; ++dd) occ |= (grid0[(4 * d2 + dd) * HWC + yx] >= 0);
        }
        int s = wave_append(occ, ctr + 1);
        if (occ) list2[s] = p;
    } else {
        int k = idx / NV;
        bool has = false;
        if (idx < 27 * NV) {
            int i = idx - k * NV;
            int4 c = reinterpret_cast<const int4*>(coors)[i];
            int kd = k / 9, r = k % 9, kh = r / 3, kw = r % 3;
            int zz = c.y + kd - 1, yy = c.z + kh - 1, xx = c.w + kw - 1;
            if ((unsigned)zz < (unsigned)D0 && (unsigned)yy < (unsigned)Hh &&
                (unsigned)xx < (unsigned)Ww)
                has = grid0[zz * HWC + yy * Ww + xx] >= 0;
        }
        wave_count(has, ctr + 8 + k);
    }
}

// ---------------- setup 3: count conv2 / conv34 / conv5 pairs ----------------
__global__ __launch_bounds__(256) void setup3_k(const int* __restrict__ grid0,
    const int* __restrict__ grid1, const int* __restrict__ list1,
    const int* __restrict__ list2, int* __restrict__ ctr) {
    int idx = blockIdx.x * 256 + threadIdx.x;
    int role = blockIdx.y;
    int n1 = ctr[0], n2 = ctr[1];
    if (role == 0) {
        int k = idx / CAPN; bool has = false;
        if (idx < 3 * CAPN) {
            int s1 = idx - k * CAPN;
            if (s1 < n1) {
                int p = list1[s1]; int d1 = p / HWC, yx = p - d1 * HWC;
                has = grid0[(2 * d1 + k) * HWC + yx] >= 0;
            }
        }
        wave_count(has, ctr + 40 + k);
    } else if (role == 1) {
        int k = idx / CAPN; bool has = false;
        if (idx < 27 * CAPN) {
            int s1 = idx - k * CAPN;
            if (s1 < n1) {
                int p = list1[s1];
                int d1 = p / HWC, yx = p - d1 * HWC, y = yx / Ww, x = yx - y * Ww;
                int kd = k / 9, r = k % 9, kh = r / 3, kw = r % 3;
                int dd = d1 + kd - 1, yy = y + kh - 1, xx = x + kw - 1;
                if ((unsigned)dd < (unsigned)ND1 && (unsigned)yy < (unsigned)Hh &&
                    (unsigned)xx < (unsigned)Ww)
                    has = grid1[dd * HWC + yy * Ww + xx] >= 0;
            }
        }
        wave_count(has, ctr + 48 + k);
    } else {
        int k = idx / CAPN; bool has = false;
        if (idx < 3 * CAPN) {
            int s2 = idx - k * CAPN;
            if (s2 < n2) {
                int p = list2[s2]; int d2 = p / HWC, yx = p - d2 * HWC;
                has = grid1[(2 * d2 + k) * HWC + yx] >= 0;
            }
        }
        wave_count(has, ctr + 80 + k);
    }
}

// ---------------- setup 4: prefix sums -> slice offsets ----------------
__global__ __launch_bounds__(64) void setup4_k(const int* __restrict__ ctr,
    int* __restrict__ soff1, int* __restrict__ soff2,
    int* __restrict__ soff34, int* __restrict__ soff5) {
    int role = blockIdx.y, s = threadIdx.x;
    const int* cnt; int* soff; int NT, F;
    switch (role) {
        case 0:  cnt = ctr + 8;  soff = soff1;  NT = 27; F = 2; break;  // conv1: 2 halves
        case 1:  cnt = ctr + 40; soff = soff2;  NT = 3;  F = 1; break;
        case 2:  cnt = ctr + 48; soff = soff34; NT = 27; F = 1; break;
        default: cnt = ctr + 80; soff = soff5;  NT = 3;  F = 1; break;
    }
    int tot = F * NT;
    if (s <= tot) {
        int sum = 0;
        for (int k = 0; k < NT; ++k) {
            int below = s - F * k;
            below = below < 0 ? 0 : (below > F ? F : below);
            sum += cnt[k] * below;
        }
        soff[s] = sum;
    }
}

// ---------------- setup 5: fill compacted pair lists ----------------
__global__ __launch_bounds__(256) void setup5_k(const int* __restrict__ coors,
    const int* __restrict__ grid0, const int* __restrict__ grid1,
    const int* __restrict__ list1, const int* __restrict__ list2,
    int* __restrict__ ctr,
    const int* __restrict__ soff1, const int* __restrict__ soff2,
    const int* __restrict__ soff34, const int* __restrict__ soff5,
    int2* __restrict__ pairs1, int2* __restrict__ pairs2,
    int2* __restrict__ pairs34, int2* __restrict__ pairs5) {
    int idx = blockIdx.x * 256 + threadIdx.x;
    int role = blockIdx.y;
    int n1 = ctr[0], n2 = ctr[1];
    if (role == 0) {
        int k = idx / NV; bool has = false; int j = -1, i = 0;
        if (idx < 27 * NV) {
            i = idx - k * NV;
            int4 c = reinterpret_cast<const int4*>(coors)[i];
            int kd = k / 9, r = k % 9, kh = r / 3, kw = r % 3;
            int zz = c.y + kd - 1, yy = c.z + kh - 1, xx = c.w + kw - 1;
            if ((unsigned)zz < (unsigned)D0 && (unsigned)yy < (unsigned)Hh &&
                (unsigned)xx < (unsigned)Ww) {
                j = grid0[zz * HWC + yy * Ww + xx];
                has = j >= 0;
            }
        }
        int rel = wave_append(has, ctr + 88 + k);
        if (has) {
            int2 pr; pr.x = j; pr.y = i;
            pairs1[soff1[2 * k] + rel]     = pr;   // half 0
            pairs1[soff1[2 * k + 1] + rel] = pr;   // half 1
        }
    } else if (role == 1) {
        int k = idx / CAPN; bool has = false; int j = -1, s1 = 0;
        if (idx < 3 * CAPN) {
            s1 = idx - k * CAPN;
            if (s1 < n1) {
                int p = list1[s1]; int d1 = p / HWC, yx = p - d1 * HWC;
                j = grid0[(2 * d1 + k) * HWC + yx];
                has = j >= 0;
            }
        }
        int rel = wave_append(has, ctr + 120 + k);
        if (has) { int2 pr; pr.x = j; pr.y = s1; pairs2[soff2[k] + rel] = pr; }
    } else if (role == 2) {
        int k = idx / CAPN; bool has = false; int j = -1, s1 = 0;
        if (idx < 27 * CAPN) {
            s1 = idx - k * CAPN;
            if (s1 < n1) {
                int p = list1[s1];
                int d1 = p / HWC, yx = p - d1 * HWC, y = yx / Ww, x = yx - y * Ww;
                int kd = k / 9, r = k % 9, kh = r / 3, kw = r % 3;
                int dd = d1 + kd - 1, yy = y + kh - 1, xx = x + kw - 1;
                if ((unsigned)dd < (unsigned)ND1 && (unsigned)yy < (unsigned)Hh &&
                    (unsigned)xx < (unsigned)Ww) {
                    j = grid1[dd * HWC + yy * Ww + xx];
                    has = j >= 0;
                }
            }
        }
        int rel = wave_append(has, ctr + 128 + k);
        if (has) { int2 pr; pr.x = j; pr.y = s1; pairs34[soff34[k] + rel] = pr; }
    } else {
        int k = idx / CAPN; bool has = false; int j = -1, s2 = 0;
        if (idx < 3 * CAPN) {
            s2 = idx - k * CAPN;
            if (s2 < n2) {
                int p = list2[s2]; int d2 = p / HWC, yx = p - d2 * HWC;
                j = grid1[(2 * d2 + k) * HWC + yx];
                has = j >= 0;
            }
        }
        int rel = wave_append(has, ctr + 160 + k);
        if (has) { int2 pr; pr.x = j; pr.y = s2; pairs5[soff5[k] + rel] = pr; }
    }
}

// ---------------- pair-batched sparse conv ----------------
// Persistent waves over compacted pair lists. lane = output channel.
// Per slice: 64-float weight column resident in VGPRs (loaded ONCE per slice
// before the pair loop). Per pair: wave-uniform x-row (scalar loads, SGPR
// operand in v_fmac) + one coalesced 256B fp32 atomic-add to the accumulator.
template<int XS, bool HALF>
__global__ __launch_bounds__(256) void pconv_k(
    const float* __restrict__ fin, const float* __restrict__ wt,
    const int2* __restrict__ pairs, const int* __restrict__ soff, int nslice,
    float* __restrict__ acc) {
    int lane = threadIdx.x & 63;
    int wid = __builtin_amdgcn_readfirstlane(
        (int)blockIdx.x * ((int)blockDim.x >> 6) + ((int)threadIdx.x >> 6));
    int nw = (int)gridDim.x * ((int)blockDim.x >> 6);
    int total = soff[nslice];
    int chunk = (total + nw - 1) / nw;
    int v0 = wid * chunk;
    int v1 = v0 + chunk; if (v1 > total) v1 = total;
    if (v0 >= v1) return;

    // binary search: last s with soff[s] <= v0
    int lo = 0, hi = nslice - 1;
    while (lo < hi) { int mid = (lo + hi + 1) >> 1; if (soff[mid] <= v0) lo = mid; else hi = mid - 1; }
    int s = lo, send = soff[s + 1];

    float w[64];
    {
        const float* wp = wt + (size_t)s * 4096 + lane;
        #pragma unroll
        for (int c = 0; c < 64; ++c) w[c] = wp[(size_t)c * 64];
    }
    int xofs = HALF ? (s & 1) * 64 : 0;

    for (int v = v0; v < v1; ++v) {
        if (v >= send) {                       // slice change (rare): reload weights
            do { ++s; send = soff[s + 1]; } while (v >= send);
            const float* wp = wt + (size_t)s * 4096 + lane;
            #pragma unroll
            for (int c = 0; c < 64; ++c) w[c] = wp[(size_t)c * 64];
            if (HALF) xofs = (s & 1) * 64;
        }
        int2 pr = pairs[v];                    // wave-uniform -> s_load
        const float* xp = fin + (size_t)pr.x * XS + xofs;
        float a0 = 0.f, a1 = 0.f, a2 = 0.f, a3 = 0.f;
        #pragma unroll
        for (int c = 0; c < 64; c += 4) {
            a0 = fmaf(xp[c],     w[c],     a0);
            a1 = fmaf(xp[c + 1], w[c + 1], a1);
            a2 = fmaf(xp[c + 2], w[c + 2], a2);
            a3 = fmaf(xp[c + 3], w[c + 3], a3);
        }
        unsafeAtomicAdd(acc + ((size_t)pr.y << 6) + lane, (a0 + a1) + (a2 + a3));
    }
}

// ---------------- BN + ReLU (+ optional accumulator re-zero) ----------------
template<bool ZERO, bool FIXEDN>
__global__ __launch_bounds__(256) void bn_k(float* __restrict__ acc,
    float* __restrict__ f, const int* __restrict__ ctr,
    const float* __restrict__ bg, const float* __restrict__ bb,
    const float* __restrict__ bm, const float* __restrict__ bv) {
    int idx = blockIdx.x * 256 + threadIdx.x;
    int site = idx >> 6, o = idx & 63;
    int n = FIXEDN ? NV : ctr[0];
    if (site < n) {
        float sc = bg[o] / sqrtf(bv[o] + EPS);
        float sh = bb[o] - bm[o] * sc;
        f[idx] = fmaxf(fmaf(acc[idx], sc, sh), 0.f);
    }
    if (ZERO) acc[idx] = 0.f;
}

// ---------------- final BN + ReLU + transpose-scatter to dense output ----------------
__global__ __launch_bounds__(256) void bn5_k(const float* __restrict__ acc5,
    const int* __restrict__ list2, const int* __restrict__ ctr,
    const float* __restrict__ bg, const float* __restrict__ bb,
    const float* __restrict__ bm, const float* __restrict__ bv,
    float* __restrict__ out) {
    __shared__ float tile[64 * 65];
    __shared__ int pp[64];
    int n2 = ctr[1];
    int sb = blockIdx.x * 64;
    int tid = threadIdx.x;
    if (tid < 64) pp[tid] = (sb + tid < n2) ? list2[sb + tid] : -1;
    int o = tid & 63;
    float sc = bg[o] / sqrtf(bv[o] + EPS);
    float sh = bb[o] - bm[o] * sc;
    __syncthreads();
    #pragma unroll
    for (int it = 0; it < 16; ++it) {          // coalesced read, BN, LDS store
        int sl = it * 4 + (tid >> 6);
        int s2 = sb + sl;
        if (s2 < n2)
            tile[sl * 65 + o] = fmaxf(fmaf(acc5[(size_t)s2 * 64 + o], sc, sh), 0.f);
    }
    __syncthreads();
    #pragma unroll
    for (int it = 0; it < 16; ++it) {          // transposed write: lanes = sites
        int og = it * 4 + (tid >> 6);
        int sl = tid & 63;
        int p = pp[sl];
        if (p >= 0) {
            int d2 = p / HWC, yx = p - d2 * HWC;
            out[(size_t)(og * ND2 + d2) * HWC + yx] = tile[sl * 65 + og];
        }
    }
}

// ---------------- launch ----------------
extern "C" void kernel_launch(void* const* d_in, const int* in_sizes, int n_in,
                              void* d_out, int out_size, void* d_ws, size_t ws_size,
                              hipStream_t stream) {
    const float* vf = (const float*)d_in[0];
    const float* w1 = (const float*)d_in[1];
    const float* w2 = (const float*)d_in[2];
    const float* w3 = (const float*)d_in[3];
    const float* w4 = (const float*)d_in[4];
    const float* w5 = (const float*)d_in[5];
    const float* bg = (const float*)d_in[6];
    const float* bb = (const float*)d_in[7];
    const float* bm = (const float*)d_in[8];
    const float* bv = (const float*)d_in[9];
    const int* coors = (const int*)d_in[10];
    float* out = (float*)d_out;

    char* ws = (char*)d_ws;
    size_t off = 0;
    auto take = [&](size_t n) -> void* {
        void* pp = ws + off;
        off += (n + 255) & ~(size_t)255;
        return pp;
    };
    // zero region: ctr + acc1 + accX + acc5 (contiguous, all 256B-multiples)
    int*   ctr  = (int*)take(1024);
    float* acc1 = (float*)take((size_t)NV * 64 * 4);       // 4.10 MB
    float* accX = (float*)take((size_t)CAPN * 64 * 4);     // 8.19 MB
    float* acc5 = (float*)take((size_t)CAPN * 64 * 4);     // 8.19 MB
    size_t zero_len = (char*)acc5 + (size_t)CAPN * 64 * 4 - (char*)ctr;
    // 0xFF region: grid0 + grid1 (contiguous)
    int*   grid0 = (int*)take((size_t)D0 * HWC * 4);       // 1.55 MB
    int*   grid1 = (int*)take((size_t)ND1 * HWC * 4);      // 0.70 MB
    size_t ff_len = (char*)grid1 + (size_t)ND1 * HWC * 4 - (char*)grid0;
    // uninitialized
    int*   list1 = (int*)take(CAPN * 4);
    int*   list2 = (int*)take(CAPN * 4);
    int*   soff1 = (int*)take(256);
    int*   soff2 = (int*)take(256);
    int*   soff34 = (int*)take(256);
    int*   soff5 = (int*)take(256);
    float* w1t = (float*)take((size_t)27 * 128 * 64 * 4);
    float* w2t = (float*)take((size_t)3 * 64 * 64 * 4);
    float* w3t = (float*)take((size_t)27 * 64 * 64 * 4);
    float* w4t = (float*)take((size_t)27 * 64 * 64 * 4);
    float* w5t = (float*)take((size_t)3 * 64 * 64 * 4);
    float* fA  = (float*)take((size_t)NV * 64 * 4);
    float* fB  = (float*)take((size_t)CAPN * 64 * 4);
    int2*  pairs1  = (int2*)take((size_t)2 * CAP1P * 8);   // 6.91 MB
    int2*  pairs2  = (int2*)take((size_t)CAP2P * 8);
    int2*  pairs34 = (int2*)take((size_t)CAP34P * 8);      // 6.91 MB
    int2*  pairs5  = (int2*)take((size_t)CAP5P * 8);

    hipMemsetAsync(ctr, 0x00, zero_len, stream);
    hipMemsetAsync(grid0, 0xFF, ff_len, stream);
    hipMemsetAsync(out, 0x00, (size_t)out_size * 4, stream);

    setup1_k<<<dim3(864, 6), 256, 0, stream>>>(coors, grid0, w1, w2, w3, w4, w5,
                                               w1t, w2t, w3t, w4t, w5t);
    setup2_k<<<dim3(1688, 3), 256, 0, stream>>>(coors, grid0, grid1, list1, list2, ctr);
    setup3_k<<<dim3(3375, 3), 256, 0, stream>>>(grid0, grid1, list1, list2, ctr);
    setup4_k<<<dim3(1, 4), 64, 0, stream>>>(ctr, soff1, soff2, soff34, soff5);
    setup5_k<<<dim3(3375, 4), 256, 0, stream>>>(coors, grid0, grid1, list1, list2, ctr,
                                                soff1, soff2, soff34, soff5,
                                                pairs1, pairs2, pairs34, pairs5);

    // conv1: 128->64 as two 64-ch halves (54 slices)
    pconv_k<128, true><<<1024, 256, 0, stream>>>(vf, w1t, pairs1, soff1, 54, acc1);
    bn_k<false, true><<<(NV * 64) / 256, 256, 0, stream>>>(acc1, fA, ctr,
        bg, bb, bm, bv);
    // conv2
    pconv_k<64, false><<<1024, 256, 0, stream>>>(fA, w2t, pairs2, soff2, 3, accX);
    bn_k<true, false><<<(CAPN * 64) / 256, 256, 0, stream>>>(accX, fB, ctr,
        bg + 64, bb + 64, bm + 64, bv + 64);
    // conv3
    pconv_k<64, false><<<1024, 256, 0, stream>>>(fB, w3t, pairs34, soff34, 27, accX);
    bn_k<true, false><<<(CAPN * 64) / 256, 256, 0, stream>>>(accX, fB, ctr,
        bg + 128, bb + 128, bm + 128, bv + 128);
    // conv4
    pconv_k<64, false><<<1024, 256, 0, stream>>>(fB, w4t, pairs34, soff34, 27, accX);
    bn_k<false, false><<<(CAPN * 64) / 256, 256, 0, stream>>>(accX, fB, ctr,
        bg + 192, bb + 192, bm + 192, bv + 192);
    // conv5
    pconv_k<64, false><<<1024, 256, 0, stream>>>(fB, w5t, pairs5, soff5, 3, acc5);
    bn5_k<<<CAPN / 64, 256, 0, stream>>>(acc5, list2, ctr,
        bg + 256, bb + 256, bm + 256, bv + 256, out);
}

// Round 4
// 422.681 us; speedup vs baseline: 1.1926x; 1.1926x over previous
//
#include <hip/hip_runtime.h>

// ---------------- problem constants ----------------
constexpr int D0  = 11;
constexpr int Hh  = 200;
constexpr int Ww  = 176;
constexpr int HWC = Hh * Ww;        // 35200
constexpr int NV  = 16000;          // 250 waves exactly (16000 % 64 == 0)
constexpr int ND1 = 5;
constexpr int ND2 = 2;
constexpr int CAPN = 32000;         // 500 waves exactly
constexpr float EPS = 1e-5f;

constexpr int CAP1P  = 432000;
constexpr int CAP34P = 864000;
constexpr int CAP2P  = 32000;
constexpr int CAP5P  = 64000;

// padded counter slots: each counter on its own 128B line
#define PC(i) ((i) << 5)
// slot map: 0:cnt1 1:cnt2 | 2+k:c1 | 29+k:c2 | 32+k:c34 | 59+k:c5
//           62+k:cur1 | 89+k:cur2 | 92+k:cur34 | 119+k:cur5   (122 slots, 15.6 KB)

// ---------------- wave/block-aggregated helpers ----------------
__device__ inline void wave_count(bool has, int* counter) {
    unsigned long long m = __ballot(has);
    int lane = threadIdx.x & 63;
    if (m && lane == __builtin_ctzll(m)) atomicAdd(counter, (int)__popcll(m));
}

__device__ inline int wave_append(bool has, int* counter) {
    unsigned long long m = __ballot(has);
    if (!m) return -1;
    int lane = threadIdx.x & 63;
    int leader = __builtin_ctzll(m);
    int base = 0;
    if (lane == leader) base = atomicAdd(counter, (int)__popcll(m));
    base = __shfl(base, leader);
    return has ? base + (int)__popcll(m & ((1ull << lane) - 1)) : -1;
}

// one atomic per 256-thread block (4 waves), LDS prefix for slots
__device__ inline int block_append(bool has, int* counter, int* lds) {
    int tid = threadIdx.x;
    int w = tid >> 6, lane = tid & 63;
    unsigned long long m = __ballot(has);
    if (lane == 0) lds[w] = (int)__popcll(m);
    __syncthreads();
    if (tid == 0) {
        int t0 = lds[0], t1 = lds[1], t2 = lds[2], t3 = lds[3];
        int base = atomicAdd(counter, t0 + t1 + t2 + t3);
        lds[4] = base;
        lds[5] = base + t0;
        lds[6] = base + t0 + t1;
        lds[7] = base + t0 + t1 + t2;
    }
    __syncthreads();
    int base = lds[4 + w];
    return has ? base + (int)__popcll(m & ((1ull << lane) - 1)) : -1;
}

// ---------------- setup 1: scatter coors + weight transposes ----------------
__global__ __launch_bounds__(256) void setup1_k(const int* __restrict__ coors,
    int* __restrict__ grid0,
    const float* __restrict__ w1, const float* __restrict__ w2,
    const float* __restrict__ w3, const float* __restrict__ w4,
    const float* __restrict__ w5,
    float* __restrict__ w1t, float* __restrict__ w2t, float* __restrict__ w3t,
    float* __restrict__ w4t, float* __restrict__ w5t) {
    int idx = blockIdx.x * 256 + threadIdx.x;
    int role = blockIdx.y;
    if (role == 0) {
        if (idx < NV) {
            int4 c = reinterpret_cast<const int4*>(coors)[idx];
            grid0[c.y * HWC + c.z * Ww + c.w] = idx;
        }
        return;
    }
    const float* src; float* dst; int I, K;
    switch (role) {
        case 1:  src = w1; dst = w1t; I = 128; K = 27; break;
        case 2:  src = w2; dst = w2t; I = 64;  K = 3;  break;
        case 3:  src = w3; dst = w3t; I = 64;  K = 27; break;
        case 4:  src = w4; dst = w4t; I = 64;  K = 27; break;
        default: src = w5; dst = w5t; I = 64;  K = 3;  break;
    }
    int tot = 64 * I * K;
    if (idx >= tot) return;
    int o = idx / (I * K), r = idx % (I * K), ii = r / K, k = r % K;
    dst[(k * I + ii) * 64 + o] = src[idx];   // wt[k][i][o]
}

// ---------------- setup 2: level-1/2 lists + count conv1 pairs ----------------
__global__ __launch_bounds__(256) void setup2_k(const int* __restrict__ coors,
    const int* __restrict__ grid0, int* __restrict__ grid1,
    int* __restrict__ list1, int* __restrict__ list2, int* __restrict__ ctr) {
    __shared__ int lds[8];
    int idx = blockIdx.x * 256 + threadIdx.x;
    int role = blockIdx.y;
    if (role == 0) {
        bool occ = false; int p = idx;
        if (p < ND1 * HWC) {
            int d1 = p / HWC, yx = p - d1 * HWC;
            int b = (2 * d1) * HWC + yx;
            occ = (grid0[b] >= 0) || (grid0[b + HWC] >= 0) || (grid0[b + 2 * HWC] >= 0);
        }
        int s = block_append(occ, ctr + PC(0), lds);
        if (occ) { grid1[p] = s; list1[s] = p; }
    } else if (role == 1) {
        bool occ = false; int p = idx;
        if (p < ND2 * HWC) {
            int d2 = p / HWC, yx = p - d2 * HWC;
            #pragma unroll
            for (int dd = 0; dd < 7; ++dd) occ |= (grid0[(4 * d2 + dd) * HWC + yx] >= 0);
        }
        int s = block_append(occ, ctr + PC(1), lds);
        if (occ) list2[s] = p;
    } else {
        int k = idx / NV;
        bool has = false;
        if (idx < 27 * NV) {
            int i = idx - k * NV;
            int4 c = reinterpret_cast<const int4*>(coors)[i];
            int kd = k / 9, r = k % 9, kh = r / 3, kw = r % 3;
            int zz = c.y + kd - 1, yy = c.z + kh - 1, xx = c.w + kw - 1;
            if ((unsigned)zz < (unsigned)D0 && (unsigned)yy < (unsigned)Hh &&
                (unsigned)xx < (unsigned)Ww)
                has = grid0[zz * HWC + yy * Ww + xx] >= 0;
        }
        wave_count(has, ctr + PC(2 + k));
    }
}

// ---------------- setup 3: count conv2 / conv34 / conv5 pairs ----------------
__global__ __launch_bounds__(256) void setup3_k(const int* __restrict__ grid0,
    const int* __restrict__ grid1, const int* __restrict__ list1,
    const int* __restrict__ list2, int* __restrict__ ctr) {
    int idx = blockIdx.x * 256 + threadIdx.x;
    int role = blockIdx.y;
    int n1 = ctr[PC(0)], n2 = ctr[PC(1)];
    if (role == 0) {
        int k = idx / CAPN; bool has = false;
        if (idx < 3 * CAPN) {
            int s1 = idx - k * CAPN;
            if (s1 < n1) {
                int p = list1[s1]; int d1 = p / HWC, yx = p - d1 * HWC;
                has = grid0[(2 * d1 + k) * HWC + yx] >= 0;
            }
        }
        wave_count(has, ctr + PC(29 + k));
    } else if (role == 1) {
        int k = idx / CAPN; bool has = false;
        if (idx < 27 * CAPN) {
            int s1 = idx - k * CAPN;
            if (s1 < n1) {
                int p = list1[s1];
                int d1 = p / HWC, yx = p - d1 * HWC, y = yx / Ww, x = yx - y * Ww;
                int kd = k / 9, r = k % 9, kh = r / 3, kw = r % 3;
                int dd = d1 + kd - 1, yy = y + kh - 1, xx = x + kw - 1;
                if ((unsigned)dd < (unsigned)ND1 && (unsigned)yy < (unsigned)Hh &&
                    (unsigned)xx < (unsigned)Ww)
                    has = grid1[dd * HWC + yy * Ww + xx] >= 0;
            }
        }
        wave_count(has, ctr + PC(32 + k));
    } else {
        int k = idx / CAPN; bool has = false;
        if (idx < 3 * CAPN) {
            int s2 = idx - k * CAPN;
            if (s2 < n2) {
                int p = list2[s2]; int d2 = p / HWC, yx = p - d2 * HWC;
                has = grid1[(2 * d2 + k) * HWC + yx] >= 0;
            }
        }
        wave_count(has, ctr + PC(59 + k));
    }
}

// ---------------- setup 4: prefix sums -> slice offsets ----------------
__global__ __launch_bounds__(64) void setup4_k(const int* __restrict__ ctr,
    int* __restrict__ soff1, int* __restrict__ soff2,
    int* __restrict__ soff34, int* __restrict__ soff5) {
    int role = blockIdx.y, s = threadIdx.x;
    const int* cnt; int* soff; int NT, F;
    switch (role) {
        case 0:  cnt = ctr + PC(2);  soff = soff1;  NT = 27; F = 2; break;
        case 1:  cnt = ctr + PC(29); soff = soff2;  NT = 3;  F = 1; break;
        case 2:  cnt = ctr + PC(32); soff = soff34; NT = 27; F = 1; break;
        default: cnt = ctr + PC(59); soff = soff5;  NT = 3;  F = 1; break;
    }
    int tot = F * NT;
    if (s <= tot) {
        int sum = 0;
        for (int k = 0; k < NT; ++k) {
            int below = s - F * k;
            below = below < 0 ? 0 : (below > F ? F : below);
            sum += cnt[PC(k)] * below;
        }
        soff[s] = sum;
    }
}

// ---------------- setup 5: fill compacted pair lists ----------------
__global__ __launch_bounds__(256) void setup5_k(const int* __restrict__ coors,
    const int* __restrict__ grid0, const int* __restrict__ grid1,
    const int* __restrict__ list1, const int* __restrict__ list2,
    int* __restrict__ ctr,
    const int* __restrict__ soff1, const int* __restrict__ soff2,
    const int* __restrict__ soff34, const int* __restrict__ soff5,
    int2* __restrict__ pairs1, int2* __restrict__ pairs2,
    int2* __restrict__ pairs34, int2* __restrict__ pairs5) {
    int idx = blockIdx.x * 256 + threadIdx.x;
    int role = blockIdx.y;
    int n1 = ctr[PC(0)], n2 = ctr[PC(1)];
    if (role == 0) {
        int k = idx / NV; bool has = false; int j = -1, i = 0;
        if (idx < 27 * NV) {
            i = idx - k * NV;
            int4 c = reinterpret_cast<const int4*>(coors)[i];
            int kd = k / 9, r = k % 9, kh = r / 3, kw = r % 3;
            int zz = c.y + kd - 1, yy = c.z + kh - 1, xx = c.w + kw - 1;
            if ((unsigned)zz < (unsigned)D0 && (unsigned)yy < (unsigned)Hh &&
                (unsigned)xx < (unsigned)Ww) {
                j = grid0[zz * HWC + yy * Ww + xx];
                has = j >= 0;
            }
        }
        int rel = wave_append(has, ctr + PC(62 + k));
        if (has) {
            int2 pr; pr.x = j; pr.y = i;
            pairs1[soff1[2 * k] + rel]     = pr;
            pairs1[soff1[2 * k + 1] + rel] = pr;
        }
    } else if (role == 1) {
        int k = idx / CAPN; bool has = false; int j = -1, s1 = 0;
        if (idx < 3 * CAPN) {
            s1 = idx - k * CAPN;
            if (s1 < n1) {
                int p = list1[s1]; int d1 = p / HWC, yx = p - d1 * HWC;
                j = grid0[(2 * d1 + k) * HWC + yx];
                has = j >= 0;
            }
        }
        int rel = wave_append(has, ctr + PC(89 + k));
        if (has) { int2 pr; pr.x = j; pr.y = s1; pairs2[soff2[k] + rel] = pr; }
    } else if (role == 2) {
        int k = idx / CAPN; bool has = false; int j = -1, s1 = 0;
        if (idx < 27 * CAPN) {
            s1 = idx - k * CAPN;
            if (s1 < n1) {
                int p = list1[s1];
                int d1 = p / HWC, yx = p - d1 * HWC, y = yx / Ww, x = yx - y * Ww;
                int kd = k / 9, r = k % 9, kh = r / 3, kw = r % 3;
                int dd = d1 + kd - 1, yy = y + kh - 1, xx = x + kw - 1;
                if ((unsigned)dd < (unsigned)ND1 && (unsigned)yy < (unsigned)Hh &&
                    (unsigned)xx < (unsigned)Ww) {
                    j = grid1[dd * HWC + yy * Ww + xx];
                    has = j >= 0;
                }
            }
        }
        int rel = wave_append(has, ctr + PC(92 + k));
        if (has) { int2 pr; pr.x = j; pr.y = s1; pairs34[soff34[k] + rel] = pr; }
    } else {
        int k = idx / CAPN; bool has = false; int j = -1, s2 = 0;
        if (idx < 3 * CAPN) {
            s2 = idx - k * CAPN;
            if (s2 < n2) {
                int p = list2[s2]; int d2 = p / HWC, yx = p - d2 * HWC;
                j = grid1[(2 * d2 + k) * HWC + yx];
                has = j >= 0;
            }
        }
        int rel = wave_append(has, ctr + PC(119 + k));
        if (has) { int2 pr; pr.x = j; pr.y = s2; pairs5[soff5[k] + rel] = pr; }
    }
}

// ---------------- pair-batched sparse conv ----------------
template<int XS, bool HALF>
__global__ __launch_bounds__(256) void pconv_k(
    const float* __restrict__ fin, const float* __restrict__ wt,
    const int2* __restrict__ pairs, const int* __restrict__ soff, int nslice,
    float* __restrict__ acc) {
    int lane = threadIdx.x & 63;
    int wid = (int)blockIdx.x * ((int)blockDim.x >> 6) + ((int)threadIdx.x >> 6);
    int nw = (int)gridDim.x * ((int)blockDim.x >> 6);
    int total = soff[nslice];
    int chunk = (total + nw - 1) / nw;
    int v = wid * chunk;
    int v1 = v + chunk; if (v1 > total) v1 = total;
    if (v >= v1) return;

    int lo = 0, hi = nslice - 1;
    while (lo < hi) { int mid = (lo + hi + 1) >> 1; if (soff[mid] <= v) lo = mid; else hi = mid - 1; }
    int s = lo, send = soff[s + 1];

    float w[64];
    int xofs = 0;
    bool need = true;
    while (v < v1) {
        while (v >= send) { ++s; send = soff[s + 1]; need = true; }
        if (need) {
            const float* wp = wt + (size_t)s * 4096 + lane;
            #pragma unroll
            for (int c = 0; c < 64; ++c) w[c] = wp[(size_t)c * 64];
            if (HALF) xofs = (s & 1) * 64;
            need = false;
        }
        int e = v1 < send ? v1 : send;
        // 2-pair unroll: two independent x-rows + FMA chains in flight
        for (; v + 1 < e; v += 2) {
            int2 prA = pairs[v];
            int2 prB = pairs[v + 1];
            const float* xa = fin + (size_t)prA.x * XS + xofs;
            const float* xb = fin + (size_t)prB.x * XS + xofs;
            float a0=0.f,a1=0.f,a2=0.f,a3=0.f,b0=0.f,b1=0.f,b2=0.f,b3=0.f;
            #pragma unroll
            for (int c = 0; c < 64; c += 4) {
                a0 = fmaf(xa[c],     w[c],     a0);
                a1 = fmaf(xa[c + 1], w[c + 1], a1);
                a2 = fmaf(xa[c + 2], w[c + 2], a2);
                a3 = fmaf(xa[c + 3], w[c + 3], a3);
                b0 = fmaf(xb[c],     w[c],     b0);
                b1 = fmaf(xb[c + 1], w[c + 1], b1);
                b2 = fmaf(xb[c + 2], w[c + 2], b2);
                b3 = fmaf(xb[c + 3], w[c + 3], b3);
            }
            unsafeAtomicAdd(acc + ((size_t)prA.y << 6) + lane, (a0 + a1) + (a2 + a3));
            unsafeAtomicAdd(acc + ((size_t)prB.y << 6) + lane, (b0 + b1) + (b2 + b3));
        }
        if (v < e) {
            int2 pr = pairs[v]; ++v;
            const float* xp = fin + (size_t)pr.x * XS + xofs;
            float a0=0.f,a1=0.f,a2=0.f,a3=0.f;
            #pragma unroll
            for (int c = 0; c < 64; c += 4) {
                a0 = fmaf(xp[c],     w[c],     a0);
                a1 = fmaf(xp[c + 1], w[c + 1], a1);
                a2 = fmaf(xp[c + 2], w[c + 2], a2);
                a3 = fmaf(xp[c + 3], w[c + 3], a3);
            }
            unsafeAtomicAdd(acc + ((size_t)pr.y << 6) + lane, (a0 + a1) + (a2 + a3));
        }
    }
}

// ---------------- BN + ReLU (+ optional accumulator re-zero) ----------------
template<bool ZERO, bool FIXEDN>
__global__ __launch_bounds__(256) void bn_k(float* __restrict__ acc,
    float* __restrict__ f, const int* __restrict__ ctr,
    const float* __restrict__ bg, const float* __restrict__ bb,
    const float* __restrict__ bm, const float* __restrict__ bv) {
    int idx = blockIdx.x * 256 + threadIdx.x;
    int site = idx >> 6, o = idx & 63;
    int n = FIXEDN ? NV : ctr[PC(0)];
    if (site < n) {
        float sc = bg[o] / sqrtf(bv[o] + EPS);
        float sh = bb[o] - bm[o] * sc;
        f[idx] = fmaxf(fmaf(acc[idx], sc, sh), 0.f);
    }
    if (ZERO) acc[idx] = 0.f;
}

// ---------------- final BN + ReLU + transpose-scatter ----------------
__global__ __launch_bounds__(256) void bn5_k(const float* __restrict__ acc5,
    const int* __restrict__ list2, const int* __restrict__ ctr,
    const float* __restrict__ bg, const float* __restrict__ bb,
    const float* __restrict__ bm, const float* __restrict__ bv,
    float* __restrict__ out) {
    __shared__ float tile[64 * 65];
    __shared__ int pp[64];
    int n2 = ctr[PC(1)];
    int sb = blockIdx.x * 64;
    int tid = threadIdx.x;
    if (tid < 64) pp[tid] = (sb + tid < n2) ? list2[sb + tid] : -1;
    int o = tid & 63;
    float sc = bg[o] / sqrtf(bv[o] + EPS);
    float sh = bb[o] - bm[o] * sc;
    __syncthreads();
    #pragma unroll
    for (int it = 0; it < 16; ++it) {
        int sl = it * 4 + (tid >> 6);
        int s2 = sb + sl;
        if (s2 < n2)
            tile[sl * 65 + o] = fmaxf(fmaf(acc5[(size_t)s2 * 64 + o], sc, sh), 0.f);
    }
    __syncthreads();
    #pragma unroll
    for (int it = 0; it < 16; ++it) {
        int og = it * 4 + (tid >> 6);
        int sl = tid & 63;
        int p = pp[sl];
        if (p >= 0) {
            int d2 = p / HWC, yx = p - d2 * HWC;
            out[(size_t)(og * ND2 + d2) * HWC + yx] = tile[sl * 65 + og];
        }
    }
}

// ---------------- launch ----------------
extern "C" void kernel_launch(void* const* d_in, const int* in_sizes, int n_in,
                              void* d_out, int out_size, void* d_ws, size_t ws_size,
                              hipStream_t stream) {
    const float* vf = (const float*)d_in[0];
    const float* w1 = (const float*)d_in[1];
    const float* w2 = (const float*)d_in[2];
    const float* w3 = (const float*)d_in[3];
    const float* w4 = (const float*)d_in[4];
    const float* w5 = (const float*)d_in[5];
    const float* bg = (const float*)d_in[6];
    const float* bb = (const float*)d_in[7];
    const float* bm = (const float*)d_in[8];
    const float* bv = (const float*)d_in[9];
    const int* coors = (const int*)d_in[10];
    float* out = (float*)d_out;

    char* ws = (char*)d_ws;
    size_t off = 0;
    auto take = [&](size_t n) -> void* {
        void* pp = ws + off;
        off += (n + 255) & ~(size_t)255;
        return pp;
    };
    int*   ctr  = (int*)take(16384);                       // padded counters
    float* acc1 = (float*)take((size_t)NV * 64 * 4);
    float* accX = (float*)take((size_t)CAPN * 64 * 4);
    float* acc5 = (float*)take((size_t)CAPN * 64 * 4);
    size_t zero_len = (char*)acc5 + (size_t)CAPN * 64 * 4 - (char*)ctr;
    int*   grid0 = (int*)take((size_t)D0 * HWC * 4);
    int*   grid1 = (int*)take((size_t)ND1 * HWC * 4);
    size_t ff_len = (char*)grid1 + (size_t)ND1 * HWC * 4 - (char*)grid0;
    int*   list1 = (int*)take(CAPN * 4);
    int*   list2 = (int*)take(CAPN * 4);
    int*   soff1 = (int*)take(256);
    int*   soff2 = (int*)take(256);
    int*   soff34 = (int*)take(256);
    int*   soff5 = (int*)take(256);
    float* w1t = (float*)take((size_t)27 * 128 * 64 * 4);
    float* w2t = (float*)take((size_t)3 * 64 * 64 * 4);
    float* w3t = (float*)take((size_t)27 * 64 * 64 * 4);
    float* w4t = (float*)take((size_t)27 * 64 * 64 * 4);
    float* w5t = (float*)take((size_t)3 * 64 * 64 * 4);
    float* fA  = (float*)take((size_t)NV * 64 * 4);
    float* fB  = (float*)take((size_t)CAPN * 64 * 4);
    int2*  pairs1  = (int2*)take((size_t)2 * CAP1P * 8);
    int2*  pairs2  = (int2*)take((size_t)CAP2P * 8);
    int2*  pairs34 = (int2*)take((size_t)CAP34P * 8);
    int2*  pairs5  = (int2*)take((size_t)CAP5P * 8);

    hipMemsetAsync(ctr, 0x00, zero_len, stream);
    hipMemsetAsync(grid0, 0xFF, ff_len, stream);
    hipMemsetAsync(out, 0x00, (size_t)out_size * 4, stream);

    setup1_k<<<dim3(864, 6), 256, 0, stream>>>(coors, grid0, w1, w2, w3, w4, w5,
                                               w1t, w2t, w3t, w4t, w5t);
    setup2_k<<<dim3(1688, 3), 256, 0, stream>>>(coors, grid0, grid1, list1, list2, ctr);
    setup3_k<<<dim3(3375, 3), 256, 0, stream>>>(grid0, grid1, list1, list2, ctr);
    setup4_k<<<dim3(1, 4), 64, 0, stream>>>(ctr, soff1, soff2, soff34, soff5);
    setup5_k<<<dim3(3375, 4), 256, 0, stream>>>(coors, grid0, grid1, list1, list2, ctr,
                                                soff1, soff2, soff34, soff5,
                                                pairs1, pairs2, pairs34, pairs5);

    // conv1: 128->64 as two 64-ch halves (54 slices)
    pconv_k<128, true><<<1024, 256, 0, stream>>>(vf, w1t, pairs1, soff1, 54, acc1);
    bn_k<false, true><<<(NV * 64) / 256, 256, 0, stream>>>(acc1, fA, ctr,
        bg, bb, bm, bv);
    // conv2
    pconv_k<64, false><<<1024, 256, 0, stream>>>(fA, w2t, pairs2, soff2, 3, accX);
    bn_k<true, false><<<(CAPN * 64) / 256, 256, 0, stream>>>(accX, fB, ctr,
        bg + 64, bb + 64, bm + 64, bv + 64);
    // conv3
    pconv_k<64, false><<<1024, 256, 0, stream>>>(fB, w3t, pairs34, soff34, 27, accX);
    bn_k<true, false><<<(CAPN * 64) / 256, 256, 0, stream>>>(accX, fB, ctr,
        bg + 128, bb + 128, bm + 128, bv + 128);
    // conv4
    pconv_k<64, false><<<1024, 256, 0, stream>>>(fB, w4t, pairs34, soff34, 27, accX);
    bn_k<false, false><<<(CAPN * 64) / 256, 256, 0, stream>>>(accX, fB, ctr,
        bg + 192, bb + 192, bm + 192, bv + 192);
    // conv5
    pconv_k<64, false><<<1024, 256, 0, stream>>>(fB, w5t, pairs5, soff5, 3, acc5);
    bn5_k<<<CAPN / 64, 256, 0, stream>>>(acc5, list2, ctr,
        bg + 256, bb + 256, bm + 256, bv + 256, out);
}

// Round 5
// 279.934 us; speedup vs baseline: 1.8007x; 1.5099x over previous
//
#include <hip/hip_runtime.h>

// ---------------- problem constants ----------------
constexpr int D0  = 11;
constexpr int Hh  = 200;
constexpr int Ww  = 176;
constexpr int HWC = Hh * Ww;        // 35200
constexpr int NV  = 16000;
constexpr int ND1 = 5;
constexpr int ND2 = 2;
constexpr int CAPN = 32000;
constexpr float EPS = 1e-5f;

constexpr int CAP1P  = 432000;
constexpr int CAP34P = 864000;
constexpr int CAP2P  = 32000;
constexpr int CAP5P  = 64000;

// padded counter slots: each counter on its own 128B line
#define PC(i) ((i) << 5)
// slot map: 0:cnt1 1:cnt2 | 2+k:c1 | 29+k:c2 | 32+k:c34 | 59+k:c5
//           62+k:cur1 | 89+k:cur2 | 92+k:cur34 | 119+k:cur5

// ---------------- wave/block-aggregated helpers ----------------
__device__ inline void wave_count(bool has, int* counter) {
    unsigned long long m = __ballot(has);
    int lane = threadIdx.x & 63;
    if (m && lane == __builtin_ctzll(m)) atomicAdd(counter, (int)__popcll(m));
}

__device__ inline int wave_append(bool has, int* counter) {
    unsigned long long m = __ballot(has);
    if (!m) return -1;
    int lane = threadIdx.x & 63;
    int leader = __builtin_ctzll(m);
    int base = 0;
    if (lane == leader) base = atomicAdd(counter, (int)__popcll(m));
    base = __shfl(base, leader);
    return has ? base + (int)__popcll(m & ((1ull << lane) - 1)) : -1;
}

__device__ inline int block_append(bool has, int* counter, int* lds) {
    int tid = threadIdx.x;
    int w = tid >> 6, lane = tid & 63;
    unsigned long long m = __ballot(has);
    if (lane == 0) lds[w] = (int)__popcll(m);
    __syncthreads();
    if (tid == 0) {
        int t0 = lds[0], t1 = lds[1], t2 = lds[2], t3 = lds[3];
        int base = atomicAdd(counter, t0 + t1 + t2 + t3);
        lds[4] = base;
        lds[5] = base + t0;
        lds[6] = base + t0 + t1;
        lds[7] = base + t0 + t1 + t2;
    }
    __syncthreads();
    int base = lds[4 + w];
    return has ? base + (int)__popcll(m & ((1ull << lane) - 1)) : -1;
}

// ---------------- setup 1: scatter coors + weight transposes ----------------
__global__ __launch_bounds__(256) void setup1_k(const int* __restrict__ coors,
    int* __restrict__ grid0,
    const float* __restrict__ w1, const float* __restrict__ w2,
    const float* __restrict__ w3, const float* __restrict__ w4,
    const float* __restrict__ w5,
    float* __restrict__ w1t, float* __restrict__ w2t, float* __restrict__ w3t,
    float* __restrict__ w4t, float* __restrict__ w5t) {
    int idx = blockIdx.x * 256 + threadIdx.x;
    int role = blockIdx.y;
    if (role == 0) {
        if (idx < NV) {
            int4 c = reinterpret_cast<const int4*>(coors)[idx];
            grid0[c.y * HWC + c.z * Ww + c.w] = idx;
        }
        return;
    }
    const float* src; float* dst; int I, K;
    switch (role) {
        case 1:  src = w1; dst = w1t; I = 128; K = 27; break;
        case 2:  src = w2; dst = w2t; I = 64;  K = 3;  break;
        case 3:  src = w3; dst = w3t; I = 64;  K = 27; break;
        case 4:  src = w4; dst = w4t; I = 64;  K = 27; break;
        default: src = w5; dst = w5t; I = 64;  K = 3;  break;
    }
    int tot = 64 * I * K;
    if (idx >= tot) return;
    int o = idx / (I * K), r = idx % (I * K), ii = r / K, k = r % K;
    dst[(k * I + ii) * 64 + o] = src[idx];   // wt[k][i][o]
}

// ---------------- setup 2: level-1/2 lists + count conv1 pairs ----------------
__global__ __launch_bounds__(256) void setup2_k(const int* __restrict__ coors,
    const int* __restrict__ grid0, int* __restrict__ grid1,
    int* __restrict__ list1, int* __restrict__ list2, int* __restrict__ ctr) {
    __shared__ int lds[8];
    int idx = blockIdx.x * 256 + threadIdx.x;
    int role = blockIdx.y;
    if (role == 0) {
        bool occ = false; int p = idx;
        if (p < ND1 * HWC) {
            int d1 = p / HWC, yx = p - d1 * HWC;
            int b = (2 * d1) * HWC + yx;
            occ = (grid0[b] >= 0) || (grid0[b + HWC] >= 0) || (grid0[b + 2 * HWC] >= 0);
        }
        int s = block_append(occ, ctr + PC(0), lds);
        if (occ) { grid1[p] = s; list1[s] = p; }
    } else if (role == 1) {
        bool occ = false; int p = idx;
        if (p < ND2 * HWC) {
            int d2 = p / HWC, yx = p - d2 * HWC;
            #pragma unroll
            for (int dd = 0; dd < 7; ++dd) occ |= (grid0[(4 * d2 + dd) * HWC + yx] >= 0);
        }
        int s = block_append(occ, ctr + PC(1), lds);
        if (occ) list2[s] = p;
    } else {
        int k = idx / NV;
        bool has = false;
        if (idx < 27 * NV) {
            int i = idx - k * NV;
            int4 c = reinterpret_cast<const int4*>(coors)[i];
            int kd = k / 9, r = k % 9, kh = r / 3, kw = r % 3;
            int zz = c.y + kd - 1, yy = c.z + kh - 1, xx = c.w + kw - 1;
            if ((unsigned)zz < (unsigned)D0 && (unsigned)yy < (unsigned)Hh &&
                (unsigned)xx < (unsigned)Ww)
                has = grid0[zz * HWC + yy * Ww + xx] >= 0;
        }
        wave_count(has, ctr + PC(2 + k));
    }
}

// ---------------- setup 3: count conv2 / conv34 / conv5 pairs ----------------
__global__ __launch_bounds__(256) void setup3_k(const int* __restrict__ grid0,
    const int* __restrict__ grid1, const int* __restrict__ list1,
    const int* __restrict__ list2, int* __restrict__ ctr) {
    int idx = blockIdx.x * 256 + threadIdx.x;
    int role = blockIdx.y;
    int n1 = ctr[PC(0)], n2 = ctr[PC(1)];
    if (role == 0) {
        int k = idx / CAPN; bool has = false;
        if (idx < 3 * CAPN) {
            int s1 = idx - k * CAPN;
            if (s1 < n1) {
                int p = list1[s1]; int d1 = p / HWC, yx = p - d1 * HWC;
                has = grid0[(2 * d1 + k) * HWC + yx] >= 0;
            }
        }
        wave_count(has, ctr + PC(29 + k));
    } else if (role == 1) {
        int k = idx / CAPN; bool has = false;
        if (idx < 27 * CAPN) {
            int s1 = idx - k * CAPN;
            if (s1 < n1) {
                int p = list1[s1];
                int d1 = p / HWC, yx = p - d1 * HWC, y = yx / Ww, x = yx - y * Ww;
                int kd = k / 9, r = k % 9, kh = r / 3, kw = r % 3;
                int dd = d1 + kd - 1, yy = y + kh - 1, xx = x + kw - 1;
                if ((unsigned)dd < (unsigned)ND1 && (unsigned)yy < (unsigned)Hh &&
                    (unsigned)xx < (unsigned)Ww)
                    has = grid1[dd * HWC + yy * Ww + xx] >= 0;
            }
        }
        wave_count(has, ctr + PC(32 + k));
    } else {
        int k = idx / CAPN; bool has = false;
        if (idx < 3 * CAPN) {
            int s2 = idx - k * CAPN;
            if (s2 < n2) {
                int p = list2[s2]; int d2 = p / HWC, yx = p - d2 * HWC;
                has = grid1[(2 * d2 + k) * HWC + yx] >= 0;
            }
        }
        wave_count(has, ctr + PC(59 + k));
    }
}

// ---------------- setup 4: prefix sums -> slice offsets ----------------
__global__ __launch_bounds__(64) void setup4_k(const int* __restrict__ ctr,
    int* __restrict__ soff1, int* __restrict__ soff2,
    int* __restrict__ soff34, int* __restrict__ soff5) {
    int role = blockIdx.y, s = threadIdx.x;
    const int* cnt; int* soff; int NT, F;
    switch (role) {
        case 0:  cnt = ctr + PC(2);  soff = soff1;  NT = 27; F = 2; break;
        case 1:  cnt = ctr + PC(29); soff = soff2;  NT = 3;  F = 1; break;
        case 2:  cnt = ctr + PC(32); soff = soff34; NT = 27; F = 1; break;
        default: cnt = ctr + PC(59); soff = soff5;  NT = 3;  F = 1; break;
    }
    int tot = F * NT;
    if (s <= tot) {
        int sum = 0;
        for (int k = 0; k < NT; ++k) {
            int below = s - F * k;
            below = below < 0 ? 0 : (below > F ? F : below);
            sum += cnt[PC(k)] * below;
        }
        soff[s] = sum;
    }
}

// ---------------- setup 5: fill compacted pair lists ----------------
__global__ __launch_bounds__(256) void setup5_k(const int* __restrict__ coors,
    const int* __restrict__ grid0, const int* __restrict__ grid1,
    const int* __restrict__ list1, const int* __restrict__ list2,
    int* __restrict__ ctr,
    const int* __restrict__ soff1, const int* __restrict__ soff2,
    const int* __restrict__ soff34, const int* __restrict__ soff5,
    int2* __restrict__ pairs1, int2* __restrict__ pairs2,
    int2* __restrict__ pairs34, int2* __restrict__ pairs5) {
    int idx = blockIdx.x * 256 + threadIdx.x;
    int role = blockIdx.y;
    int n1 = ctr[PC(0)], n2 = ctr[PC(1)];
    if (role == 0) {
        int k = idx / NV; bool has = false; int j = -1, i = 0;
        if (idx < 27 * NV) {
            i = idx - k * NV;
            int4 c = reinterpret_cast<const int4*>(coors)[i];
            int kd = k / 9, r = k % 9, kh = r / 3, kw = r % 3;
            int zz = c.y + kd - 1, yy = c.z + kh - 1, xx = c.w + kw - 1;
            if ((unsigned)zz < (unsigned)D0 && (unsigned)yy < (unsigned)Hh &&
                (unsigned)xx < (unsigned)Ww) {
                j = grid0[zz * HWC + yy * Ww + xx];
                has = j >= 0;
            }
        }
        int rel = wave_append(has, ctr + PC(62 + k));
        if (has) {
            int2 pr; pr.x = j; pr.y = i;
            pairs1[soff1[2 * k] + rel]     = pr;
            pairs1[soff1[2 * k + 1] + rel] = pr;
        }
    } else if (role == 1) {
        int k = idx / CAPN; bool has = false; int j = -1, s1 = 0;
        if (idx < 3 * CAPN) {
            s1 = idx - k * CAPN;
            if (s1 < n1) {
                int p = list1[s1]; int d1 = p / HWC, yx = p - d1 * HWC;
                j = grid0[(2 * d1 + k) * HWC + yx];
                has = j >= 0;
            }
        }
        int rel = wave_append(has, ctr + PC(89 + k));
        if (has) { int2 pr; pr.x = j; pr.y = s1; pairs2[soff2[k] + rel] = pr; }
    } else if (role == 2) {
        int k = idx / CAPN; bool has = false; int j = -1, s1 = 0;
        if (idx < 27 * CAPN) {
            s1 = idx - k * CAPN;
            if (s1 < n1) {
                int p = list1[s1];
                int d1 = p / HWC, yx = p - d1 * HWC, y = yx / Ww, x = yx - y * Ww;
                int kd = k / 9, r = k % 9, kh = r / 3, kw = r % 3;
                int dd = d1 + kd - 1, yy = y + kh - 1, xx = x + kw - 1;
                if ((unsigned)dd < (unsigned)ND1 && (unsigned)yy < (unsigned)Hh &&
                    (unsigned)xx < (unsigned)Ww) {
                    j = grid1[dd * HWC + yy * Ww + xx];
                    has = j >= 0;
                }
            }
        }
        int rel = wave_append(has, ctr + PC(92 + k));
        if (has) { int2 pr; pr.x = j; pr.y = s1; pairs34[soff34[k] + rel] = pr; }
    } else {
        int k = idx / CAPN; bool has = false; int j = -1, s2 = 0;
        if (idx < 3 * CAPN) {
            s2 = idx - k * CAPN;
            if (s2 < n2) {
                int p = list2[s2]; int d2 = p / HWC, yx = p - d2 * HWC;
                j = grid1[(2 * d2 + k) * HWC + yx];
                has = j >= 0;
            }
        }
        int rel = wave_append(has, ctr + PC(119 + k));
        if (has) { int2 pr; pr.x = j; pr.y = s2; pairs5[soff5[k] + rel] = pr; }
    }
}

// ---------------- pair-batched sparse conv ----------------
// lane = output channel. Per slice: 64-float weight column resident in VGPRs
// (launch_bounds(256,4) -> 128-VGPR budget, NO spill). Per pair: pair indices
// readfirstlane'd to SGPRs -> x-row is a uniform-address (scalar-load) read;
// one coalesced 256B fp32 atomic-add to the accumulator.
template<int XS, bool HALF>
__global__ __launch_bounds__(256, 4) void pconv_k(
    const float* __restrict__ fin, const float* __restrict__ wt,
    const int2* __restrict__ pairs, const int* __restrict__ soff, int nslice,
    float* __restrict__ acc) {
    const int lane = threadIdx.x & 63;
    const int wid = __builtin_amdgcn_readfirstlane(
        (int)blockIdx.x * 4 + ((int)threadIdx.x >> 6));
    const int nw = (int)gridDim.x * 4;
    const int total = soff[nslice];
    int chunk = (total + nw - 1) / nw;
    int v = wid * chunk;
    int v1 = v + chunk; if (v1 > total) v1 = total;
    if (v >= v1) return;

    int lo = 0, hi = nslice - 1;
    while (lo < hi) { int mid = (lo + hi + 1) >> 1; if (soff[mid] <= v) lo = mid; else hi = mid - 1; }
    int s = lo, send = soff[s + 1];

    float w[64];
    int xofs = 0;
    bool need = true;
    while (v < v1) {
        while (v >= send) { ++s; send = soff[s + 1]; need = true; }
        if (need) {
            const float* wp = wt + (size_t)s * 4096 + lane;
            #pragma unroll
            for (int c = 0; c < 64; ++c) w[c] = wp[(size_t)c * 64];
            if (HALF) xofs = (s & 1) * 64;
            need = false;
        }
        int e = v1 < send ? v1 : send;
        for (; v + 1 < e; v += 2) {
            int2 prA = pairs[v];
            int2 prB = pairs[v + 1];
            int ja = __builtin_amdgcn_readfirstlane(prA.x);
            int ya = __builtin_amdgcn_readfirstlane(prA.y);
            int jb = __builtin_amdgcn_readfirstlane(prB.x);
            int yb = __builtin_amdgcn_readfirstlane(prB.y);
            const float* xa = fin + (size_t)ja * XS + xofs;
            const float* xb = fin + (size_t)jb * XS + xofs;
            float a0=0.f,a1=0.f,a2=0.f,a3=0.f,b0=0.f,b1=0.f,b2=0.f,b3=0.f;
            #pragma unroll
            for (int c = 0; c < 64; c += 4) {
                a0 = fmaf(xa[c],     w[c],     a0);
                a1 = fmaf(xa[c + 1], w[c + 1], a1);
                a2 = fmaf(xa[c + 2], w[c + 2], a2);
                a3 = fmaf(xa[c + 3], w[c + 3], a3);
                b0 = fmaf(xb[c],     w[c],     b0);
                b1 = fmaf(xb[c + 1], w[c + 1], b1);
                b2 = fmaf(xb[c + 2], w[c + 2], b2);
                b3 = fmaf(xb[c + 3], w[c + 3], b3);
            }
            unsafeAtomicAdd(acc + ((size_t)ya << 6) + lane, (a0 + a1) + (a2 + a3));
            unsafeAtomicAdd(acc + ((size_t)yb << 6) + lane, (b0 + b1) + (b2 + b3));
        }
        if (v < e) {
            int2 pr = pairs[v]; ++v;
            int jp = __builtin_amdgcn_readfirstlane(pr.x);
            int yp = __builtin_amdgcn_readfirstlane(pr.y);
            const float* xp = fin + (size_t)jp * XS + xofs;
            float a0=0.f,a1=0.f,a2=0.f,a3=0.f;
            #pragma unroll
            for (int c = 0; c < 64; c += 4) {
                a0 = fmaf(xp[c],     w[c],     a0);
                a1 = fmaf(xp[c + 1], w[c + 1], a1);
                a2 = fmaf(xp[c + 2], w[c + 2], a2);
                a3 = fmaf(xp[c + 3], w[c + 3], a3);
            }
            unsafeAtomicAdd(acc + ((size_t)yp << 6) + lane, (a0 + a1) + (a2 + a3));
        }
    }
}

// ---------------- BN + ReLU (+ optional accumulator re-zero) ----------------
template<bool ZERO, bool FIXEDN>
__global__ __launch_bounds__(256) void bn_k(float* __restrict__ acc,
    float* __restrict__ f, const int* __restrict__ ctr,
    const float* __restrict__ bg, const float* __restrict__ bb,
    const float* __restrict__ bm, const float* __restrict__ bv) {
    int idx = blockIdx.x * 256 + threadIdx.x;
    int site = idx >> 6, o = idx & 63;
    int n = FIXEDN ? NV : ctr[PC(0)];
    if (site < n) {
        float sc = bg[o] / sqrtf(bv[o] + EPS);
        float sh = bb[o] - bm[o] * sc;
        f[idx] = fmaxf(fmaf(acc[idx], sc, sh), 0.f);
    }
    if (ZERO) acc[idx] = 0.f;
}

// ---------------- final BN + ReLU + transpose-scatter ----------------
__global__ __launch_bounds__(256) void bn5_k(const float* __restrict__ acc5,
    const int* __restrict__ list2, const int* __restrict__ ctr,
    const float* __restrict__ bg, const float* __restrict__ bb,
    const float* __restrict__ bm, const float* __restrict__ bv,
    float* __restrict__ out) {
    __shared__ float tile[64 * 65];
    __shared__ int pp[64];
    int n2 = ctr[PC(1)];
    int sb = blockIdx.x * 64;
    int tid = threadIdx.x;
    if (tid < 64) pp[tid] = (sb + tid < n2) ? list2[sb + tid] : -1;
    int o = tid & 63;
    float sc = bg[o] / sqrtf(bv[o] + EPS);
    float sh = bb[o] - bm[o] * sc;
    __syncthreads();
    #pragma unroll
    for (int it = 0; it < 16; ++it) {
        int sl = it * 4 + (tid >> 6);
        int s2 = sb + sl;
        if (s2 < n2)
            tile[sl * 65 + o] = fmaxf(fmaf(acc5[(size_t)s2 * 64 + o], sc, sh), 0.f);
    }
    __syncthreads();
    #pragma unroll
    for (int it = 0; it < 16; ++it) {
        int og = it * 4 + (tid >> 6);
        int sl = tid & 63;
        int p = pp[sl];
        if (p >= 0) {
            int d2 = p / HWC, yx = p - d2 * HWC;
            out[(size_t)(og * ND2 + d2) * HWC + yx] = tile[sl * 65 + og];
        }
    }
}

// ---------------- launch ----------------
extern "C" void kernel_launch(void* const* d_in, const int* in_sizes, int n_in,
                              void* d_out, int out_size, void* d_ws, size_t ws_size,
                              hipStream_t stream) {
    const float* vf = (const float*)d_in[0];
    const float* w1 = (const float*)d_in[1];
    const float* w2 = (const float*)d_in[2];
    const float* w3 = (const float*)d_in[3];
    const float* w4 = (const float*)d_in[4];
    const float* w5 = (const float*)d_in[5];
    const float* bg = (const float*)d_in[6];
    const float* bb = (const float*)d_in[7];
    const float* bm = (const float*)d_in[8];
    const float* bv = (const float*)d_in[9];
    const int* coors = (const int*)d_in[10];
    float* out = (float*)d_out;

    char* ws = (char*)d_ws;
    size_t off = 0;
    auto take = [&](size_t n) -> void* {
        void* pp = ws + off;
        off += (n + 255) & ~(size_t)255;
        return pp;
    };
    int*   ctr  = (int*)take(16384);
    float* acc1 = (float*)take((size_t)NV * 64 * 4);
    float* accX = (float*)take((size_t)CAPN * 64 * 4);
    float* acc5 = (float*)take((size_t)CAPN * 64 * 4);
    size_t zero_len = (char*)acc5 + (size_t)CAPN * 64 * 4 - (char*)ctr;
    int*   grid0 = (int*)take((size_t)D0 * HWC * 4);
    int*   grid1 = (int*)take((size_t)ND1 * HWC * 4);
    size_t ff_len = (char*)grid1 + (size_t)ND1 * HWC * 4 - (char*)grid0;
    int*   list1 = (int*)take(CAPN * 4);
    int*   list2 = (int*)take(CAPN * 4);
    int*   soff1 = (int*)take(256);
    int*   soff2 = (int*)take(256);
    int*   soff34 = (int*)take(256);
    int*   soff5 = (int*)take(256);
    float* w1t = (float*)take((size_t)27 * 128 * 64 * 4);
    float* w2t = (float*)take((size_t)3 * 64 * 64 * 4);
    float* w3t = (float*)take((size_t)27 * 64 * 64 * 4);
    float* w4t = (float*)take((size_t)27 * 64 * 64 * 4);
    float* w5t = (float*)take((size_t)3 * 64 * 64 * 4);
    float* fA  = (float*)take((size_t)NV * 64 * 4);
    float* fB  = (float*)take((size_t)CAPN * 64 * 4);
    int2*  pairs1  = (int2*)take((size_t)2 * CAP1P * 8);
    int2*  pairs2  = (int2*)take((size_t)CAP2P * 8);
    int2*  pairs34 = (int2*)take((size_t)CAP34P * 8);
    int2*  pairs5  = (int2*)take((size_t)CAP5P * 8);

    hipMemsetAsync(ctr, 0x00, zero_len, stream);
    hipMemsetAsync(grid0, 0xFF, ff_len, stream);
    hipMemsetAsync(out, 0x00, (size_t)out_size * 4, stream);

    setup1_k<<<dim3(864, 6), 256, 0, stream>>>(coors, grid0, w1, w2, w3, w4, w5,
                                               w1t, w2t, w3t, w4t, w5t);
    setup2_k<<<dim3(1688, 3), 256, 0, stream>>>(coors, grid0, grid1, list1, list2, ctr);
    setup3_k<<<dim3(3375, 3), 256, 0, stream>>>(grid0, grid1, list1, list2, ctr);
    setup4_k<<<dim3(1, 4), 64, 0, stream>>>(ctr, soff1, soff2, soff34, soff5);
    setup5_k<<<dim3(3375, 4), 256, 0, stream>>>(coors, grid0, grid1, list1, list2, ctr,
                                                soff1, soff2, soff34, soff5,
                                                pairs1, pairs2, pairs34, pairs5);

    // conv1: 128->64 as two 64-ch halves (54 slices)
    pconv_k<128, true><<<1024, 256, 0, stream>>>(vf, w1t, pairs1, soff1, 54, acc1);
    bn_k<false, true><<<(NV * 64) / 256, 256, 0, stream>>>(acc1, fA, ctr,
        bg, bb, bm, bv);
    // conv2
    pconv_k<64, false><<<1024, 256, 0, stream>>>(fA, w2t, pairs2, soff2, 3, accX);
    bn_k<true, false><<<(CAPN * 64) / 256, 256, 0, stream>>>(accX, fB, ctr,
        bg + 64, bb + 64, bm + 64, bv + 64);
    // conv3
    pconv_k<64, false><<<1024, 256, 0, stream>>>(fB, w3t, pairs34, soff34, 27, accX);
    bn_k<true, false><<<(CAPN * 64) / 256, 256, 0, stream>>>(accX, fB, ctr,
        bg + 128, bb + 128, bm + 128, bv + 128);
    // conv4
    pconv_k<64, false><<<1024, 256, 0, stream>>>(fB, w4t, pairs34, soff34, 27, accX);
    bn_k<false, false><<<(CAPN * 64) / 256, 256, 0, stream>>>(accX, fB, ctr,
        bg + 192, bb + 192, bm + 192, bv + 192);
    // conv5
    pconv_k<64, false><<<1024, 256, 0, stream>>>(fB, w5t, pairs5, soff5, 3, acc5);
    bn5_k<<<CAPN / 64, 256, 0, stream>>>(acc5, list2, ctr,
        bg + 256, bb + 256, bm + 256, bv + 256, out);
}

// Round 6
// 248.928 us; speedup vs baseline: 2.0250x; 1.1246x over previous
//
#include <hip/hip_runtime.h>

// ---------------- problem constants ----------------
constexpr int D0  = 11;
constexpr int Hh  = 200;
constexpr int Ww  = 176;
constexpr int HWC = Hh * Ww;        // 35200
constexpr int NV  = 16000;          // % 64 == 0
constexpr int ND1 = 5;
constexpr int ND2 = 2;
constexpr int CAPN = 32000;         // % 64 == 0 ; n1,n2 <= 2*NV = 32000
constexpr float EPS = 1e-5f;

// padded counter slots: each counter on its own 128B line
#define PC(i) ((i) << 5)
// slot map: 0:n1 1:n2 | 2+k (k<27): conv1 cursors/counts | 29+k (k<3): conv2
//           32+k (k<27): conv34 | 59+k (k<3): conv5

// ---------------- wave/block-aggregated helpers ----------------
__device__ inline int wave_append(bool has, int* counter) {
    unsigned long long m = __ballot(has);
    if (!m) return -1;
    int lane = threadIdx.x & 63;
    int leader = __builtin_ctzll(m);
    int base = 0;
    if (lane == leader) base = atomicAdd(counter, (int)__popcll(m));
    base = __shfl(base, leader);
    return has ? base + (int)__popcll(m & ((1ull << lane) - 1)) : -1;
}

__device__ inline int block_append(bool has, int* counter, int* lds) {
    int tid = threadIdx.x;
    int w = tid >> 6, lane = tid & 63;
    unsigned long long m = __ballot(has);
    if (lane == 0) lds[w] = (int)__popcll(m);
    __syncthreads();
    if (tid == 0) {
        int t0 = lds[0], t1 = lds[1], t2 = lds[2], t3 = lds[3];
        int base = atomicAdd(counter, t0 + t1 + t2 + t3);
        lds[4] = base;
        lds[5] = base + t0;
        lds[6] = base + t0 + t1;
        lds[7] = base + t0 + t1 + t2;
    }
    __syncthreads();
    int base = lds[4 + w];
    return has ? base + (int)__popcll(m & ((1ull << lane) - 1)) : -1;
}

// ---------------- setup 1: scatter coors + weight transposes ----------------
__global__ __launch_bounds__(256) void setup1_k(const int* __restrict__ coors,
    int* __restrict__ grid0,
    const float* __restrict__ w1, const float* __restrict__ w2,
    const float* __restrict__ w3, const float* __restrict__ w4,
    const float* __restrict__ w5,
    float* __restrict__ w1t, float* __restrict__ w2t, float* __restrict__ w3t,
    float* __restrict__ w4t, float* __restrict__ w5t) {
    int idx = blockIdx.x * 256 + threadIdx.x;
    int role = blockIdx.y;
    if (role == 0) {
        if (idx < NV) {
            int4 c = reinterpret_cast<const int4*>(coors)[idx];
            grid0[c.y * HWC + c.z * Ww + c.w] = idx;
        }
        return;
    }
    const float* src; float* dst; int I, K;
    switch (role) {
        case 1:  src = w1; dst = w1t; I = 128; K = 27; break;
        case 2:  src = w2; dst = w2t; I = 64;  K = 3;  break;
        case 3:  src = w3; dst = w3t; I = 64;  K = 27; break;
        case 4:  src = w4; dst = w4t; I = 64;  K = 27; break;
        default: src = w5; dst = w5t; I = 64;  K = 3;  break;
    }
    int tot = 64 * I * K;
    if (idx >= tot) return;
    int o = idx / (I * K), r = idx % (I * K), ii = r / K, k = r % K;
    dst[(k * I + ii) * 64 + o] = src[idx];   // wt[k][i][o]
}

// ---------------- setup 2: lists + conv1 pair fill ----------------
// flattened roles: [0,688) list1/grid1 | [688,963) list2 | [963,2651) conv1 fill
__global__ __launch_bounds__(256) void setup2_k(const int* __restrict__ coors,
    const int* __restrict__ grid0, int* __restrict__ grid1,
    int* __restrict__ list1, int* __restrict__ list2, int* __restrict__ ctr,
    int2* __restrict__ pairs1) {
    __shared__ int lds[8];
    int bid = blockIdx.x, tid = threadIdx.x;
    if (bid < 688) {
        int p = bid * 256 + tid;
        bool occ = false;
        if (p < ND1 * HWC) {
            int d1 = p / HWC, yx = p - d1 * HWC;
            int b = (2 * d1) * HWC + yx;
            occ = (grid0[b] >= 0) || (grid0[b + HWC] >= 0) || (grid0[b + 2 * HWC] >= 0);
        }
        int s = block_append(occ, ctr + PC(0), lds);
        if (occ) { grid1[p] = s; list1[s] = p; }
    } else if (bid < 963) {
        int p = (bid - 688) * 256 + tid;
        bool occ = false;
        if (p < ND2 * HWC) {
            int d2 = p / HWC, yx = p - d2 * HWC;
            #pragma unroll
            for (int dd = 0; dd < 7; ++dd) occ |= (grid0[(4 * d2 + dd) * HWC + yx] >= 0);
        }
        int s = block_append(occ, ctr + PC(1), lds);
        if (occ) list2[s] = p;
    } else {
        int idx = (bid - 963) * 256 + tid;       // < 432128; 27*NV = 432000
        int k = idx / NV;                        // wave-uniform (NV % 64 == 0)
        bool has = false; int j = -1;
        int i = idx - k * NV;
        if (idx < 27 * NV) {
            int4 c = reinterpret_cast<const int4*>(coors)[i];
            int kd = k / 9, r = k % 9, kh = r / 3, kw = r % 3;
            int zz = c.y + kd - 1, yy = c.z + kh - 1, xx = c.w + kw - 1;
            if ((unsigned)zz < (unsigned)D0 && (unsigned)yy < (unsigned)Hh &&
                (unsigned)xx < (unsigned)Ww) {
                j = grid0[zz * HWC + yy * Ww + xx];
                has = j >= 0;
            }
        }
        int rel = wave_append(has, ctr + PC(2 + k));   // no atomic if ballot==0
        if (has) { int2 pr; pr.x = j; pr.y = i; pairs1[k * NV + rel] = pr; }
    }
}

// ---------------- setup 3: conv2 / conv34 / conv5 pair fills ----------------
// flattened roles: [0,375) conv2 | [375,3750) conv34 | [3750,4125) conv5
__global__ __launch_bounds__(256) void setup3_k(const int* __restrict__ grid0,
    const int* __restrict__ grid1, const int* __restrict__ list1,
    const int* __restrict__ list2, int* __restrict__ ctr,
    int2* __restrict__ pairs2, int2* __restrict__ pairs34,
    int2* __restrict__ pairs5) {
    int bid = blockIdx.x, tid = threadIdx.x;
    int n1 = ctr[PC(0)], n2 = ctr[PC(1)];
    if (bid < 375) {
        int idx = bid * 256 + tid;               // 3*CAPN exact
        int k = idx / CAPN;                      // wave-uniform
        int s1 = idx - k * CAPN;
        bool has = false; int j = -1;
        if (s1 < n1) {
            int p = list1[s1]; int d1 = p / HWC, yx = p - d1 * HWC;
            j = grid0[(2 * d1 + k) * HWC + yx];
            has = j >= 0;
        }
        int rel = wave_append(has, ctr + PC(29 + k));
        if (has) { int2 pr; pr.x = j; pr.y = s1; pairs2[k * CAPN + rel] = pr; }
    } else if (bid < 3750) {
        int idx = (bid - 375) * 256 + tid;       // 27*CAPN exact
        int k = idx / CAPN;
        int s1 = idx - k * CAPN;
        bool has = false; int j = -1;
        if (s1 < n1) {
            int p = list1[s1];
            int d1 = p / HWC, yx = p - d1 * HWC, y = yx / Ww, x = yx - y * Ww;
            int kd = k / 9, r = k % 9, kh = r / 3, kw = r % 3;
            int dd = d1 + kd - 1, yy = y + kh - 1, xx = x + kw - 1;
            if ((unsigned)dd < (unsigned)ND1 && (unsigned)yy < (unsigned)Hh &&
                (unsigned)xx < (unsigned)Ww) {
                j = grid1[dd * HWC + yy * Ww + xx];
                has = j >= 0;
            }
        }
        int rel = wave_append(has, ctr + PC(32 + k));
        if (has) { int2 pr; pr.x = j; pr.y = s1; pairs34[k * CAPN + rel] = pr; }
    } else {
        int idx = (bid - 3750) * 256 + tid;      // 3*CAPN exact
        int k = idx / CAPN;
        int s2 = idx - k * CAPN;
        bool has = false; int j = -1;
        if (s2 < n2) {
            int p = list2[s2]; int d2 = p / HWC, yx = p - d2 * HWC;
            j = grid1[(2 * d2 + k) * HWC + yx];
            has = j >= 0;
        }
        int rel = wave_append(has, ctr + PC(59 + k));
        if (has) { int2 pr; pr.x = j; pr.y = s2; pairs5[k * CAPN + rel] = pr; }
    }
}

// ---------------- pair-batched sparse conv ----------------
// Strided per-tap pair lists; per-wave slice walk using the fill cursors as
// counts (scalar loads). lane = output channel; weight column resident in
// VGPRs; x-row via uniform scalar loads; 256B fp32 atomic-add accumulate.
template<int XS, bool HALF, int NT, int STRIDE>
__global__ __launch_bounds__(256, 4) void pconv_k(
    const float* __restrict__ fin, const float* __restrict__ wt,
    const int2* __restrict__ pairs, const int* __restrict__ cnt,
    float* __restrict__ acc) {
    const int lane = threadIdx.x & 63;
    const int wid = __builtin_amdgcn_readfirstlane(
        (int)blockIdx.x * 4 + ((int)threadIdx.x >> 6));
    const int nw = (int)gridDim.x * 4;

    int sum = 0;
    #pragma unroll
    for (int k = 0; k < NT; ++k) sum += cnt[k << 5];
    const int total = HALF ? 2 * sum : sum;

    int chunk = (total + nw - 1) / nw;
    int v = wid * chunk;
    int v1 = v + chunk; if (v1 > total) v1 = total;
    if (v >= v1) return;

    // walk to the slice containing v
    int s = 0, soff_s = 0;
    int send = cnt[0];
    while (v >= send) { soff_s = send; ++s; send += cnt[(HALF ? (s >> 1) : s) << 5]; }

    float w[64];
    int xofs = 0;
    const int2* pb = nullptr;
    bool need = true;
    while (v < v1) {
        while (v >= send) { soff_s = send; ++s; send += cnt[(HALF ? (s >> 1) : s) << 5]; need = true; }
        if (need) {
            const float* wp = wt + (size_t)s * 4096 + lane;   // HALF: s=2k+h -> k*8192+h*4096
            #pragma unroll
            for (int c = 0; c < 64; ++c) w[c] = wp[(size_t)c * 64];
            if (HALF) xofs = (s & 1) * 64;
            pb = pairs + (size_t)(HALF ? (s >> 1) : s) * STRIDE - soff_s;
            need = false;
        }
        int e = v1 < send ? v1 : send;
        for (; v + 1 < e; v += 2) {
            int2 prA = pb[v];
            int2 prB = pb[v + 1];
            int ja = __builtin_amdgcn_readfirstlane(prA.x);
            int ya = __builtin_amdgcn_readfirstlane(prA.y);
            int jb = __builtin_amdgcn_readfirstlane(prB.x);
            int yb = __builtin_amdgcn_readfirstlane(prB.y);
            const float* xa = fin + (size_t)ja * XS + xofs;
            const float* xb = fin + (size_t)jb * XS + xofs;
            float a0=0.f,a1=0.f,a2=0.f,a3=0.f,b0=0.f,b1=0.f,b2=0.f,b3=0.f;
            #pragma unroll
            for (int c = 0; c < 64; c += 4) {
                a0 = fmaf(xa[c],     w[c],     a0);
                a1 = fmaf(xa[c + 1], w[c + 1], a1);
                a2 = fmaf(xa[c + 2], w[c + 2], a2);
                a3 = fmaf(xa[c + 3], w[c + 3], a3);
                b0 = fmaf(xb[c],     w[c],     b0);
                b1 = fmaf(xb[c + 1], w[c + 1], b1);
                b2 = fmaf(xb[c + 2], w[c + 2], b2);
                b3 = fmaf(xb[c + 3], w[c + 3], b3);
            }
            unsafeAtomicAdd(acc + ((size_t)ya << 6) + lane, (a0 + a1) + (a2 + a3));
            unsafeAtomicAdd(acc + ((size_t)yb << 6) + lane, (b0 + b1) + (b2 + b3));
        }
        if (v < e) {
            int2 pr = pb[v]; ++v;
            int jp = __builtin_amdgcn_readfirstlane(pr.x);
            int yp = __builtin_amdgcn_readfirstlane(pr.y);
            const float* xp = fin + (size_t)jp * XS + xofs;
            float a0=0.f,a1=0.f,a2=0.f,a3=0.f;
            #pragma unroll
            for (int c = 0; c < 64; c += 4) {
                a0 = fmaf(xp[c],     w[c],     a0);
                a1 = fmaf(xp[c + 1], w[c + 1], a1);
                a2 = fmaf(xp[c + 2], w[c + 2], a2);
                a3 = fmaf(xp[c + 3], w[c + 3], a3);
            }
            unsafeAtomicAdd(acc + ((size_t)yp << 6) + lane, (a0 + a1) + (a2 + a3));
        }
    }
}

// ---------------- BN + ReLU (+ bounded accumulator re-zero) ----------------
template<bool ZERO, bool FIXEDN>
__global__ __launch_bounds__(256) void bn_k(float* __restrict__ acc,
    float* __restrict__ f, const int* __restrict__ ctr,
    const float* __restrict__ bg, const float* __restrict__ bb,
    const float* __restrict__ bm, const float* __restrict__ bv) {
    int idx = blockIdx.x * 256 + threadIdx.x;
    int site = idx >> 6, o = idx & 63;
    int n = FIXEDN ? NV : ctr[PC(0)];
    if (site < n) {
        float sc = bg[o] / sqrtf(bv[o] + EPS);
        float sh = bb[o] - bm[o] * sc;
        f[idx] = fmaxf(fmaf(acc[idx], sc, sh), 0.f);
        if (ZERO) acc[idx] = 0.f;
    }
}

// ---------------- final BN + ReLU + transpose-scatter ----------------
__global__ __launch_bounds__(256) void bn5_k(const float* __restrict__ acc5,
    const int* __restrict__ list2, const int* __restrict__ ctr,
    const float* __restrict__ bg, const float* __restrict__ bb,
    const float* __restrict__ bm, const float* __restrict__ bv,
    float* __restrict__ out) {
    __shared__ float tile[64 * 65];
    __shared__ int pp[64];
    int n2 = ctr[PC(1)];
    int sb = blockIdx.x * 64;
    int tid = threadIdx.x;
    if (tid < 64) pp[tid] = (sb + tid < n2) ? list2[sb + tid] : -1;
    int o = tid & 63;
    float sc = bg[o] / sqrtf(bv[o] + EPS);
    float sh = bb[o] - bm[o] * sc;
    __syncthreads();
    #pragma unroll
    for (int it = 0; it < 16; ++it) {
        int sl = it * 4 + (tid >> 6);
        int s2 = sb + sl;
        if (s2 < n2)
            tile[sl * 65 + o] = fmaxf(fmaf(acc5[(size_t)s2 * 64 + o], sc, sh), 0.f);
    }
    __syncthreads();
    #pragma unroll
    for (int it = 0; it < 16; ++it) {
        int og = it * 4 + (tid >> 6);
        int sl = tid & 63;
        int p = pp[sl];
        if (p >= 0) {
            int d2 = p / HWC, yx = p - d2 * HWC;
            out[(size_t)(og * ND2 + d2) * HWC + yx] = tile[sl * 65 + og];
        }
    }
}

// ---------------- launch ----------------
extern "C" void kernel_launch(void* const* d_in, const int* in_sizes, int n_in,
                              void* d_out, int out_size, void* d_ws, size_t ws_size,
                              hipStream_t stream) {
    const float* vf = (const float*)d_in[0];
    const float* w1 = (const float*)d_in[1];
    const float* w2 = (const float*)d_in[2];
    const float* w3 = (const float*)d_in[3];
    const float* w4 = (const float*)d_in[4];
    const float* w5 = (const float*)d_in[5];
    const float* bg = (const float*)d_in[6];
    const float* bb = (const float*)d_in[7];
    const float* bm = (const float*)d_in[8];
    const float* bv = (const float*)d_in[9];
    const int* coors = (const int*)d_in[10];
    float* out = (float*)d_out;

    char* ws = (char*)d_ws;
    size_t off = 0;
    auto take = [&](size_t n) -> void* {
        void* pp = ws + off;
        off += (n + 255) & ~(size_t)255;
        return pp;
    };
    int*   ctr  = (int*)take(16384);
    float* acc1 = (float*)take((size_t)NV * 64 * 4);
    float* accX = (float*)take((size_t)CAPN * 64 * 4);
    float* acc5 = (float*)take((size_t)CAPN * 64 * 4);
    size_t zero_len = (char*)acc5 + (size_t)CAPN * 64 * 4 - (char*)ctr;
    int*   grid0 = (int*)take((size_t)D0 * HWC * 4);
    int*   grid1 = (int*)take((size_t)ND1 * HWC * 4);
    size_t ff_len = (char*)grid1 + (size_t)ND1 * HWC * 4 - (char*)grid0;
    int*   list1 = (int*)take(CAPN * 4);
    int*   list2 = (int*)take(CAPN * 4);
    float* w1t = (float*)take((size_t)27 * 128 * 64 * 4);
    float* w2t = (float*)take((size_t)3 * 64 * 64 * 4);
    float* w3t = (float*)take((size_t)27 * 64 * 64 * 4);
    float* w4t = (float*)take((size_t)27 * 64 * 64 * 4);
    float* w5t = (float*)take((size_t)3 * 64 * 64 * 4);
    float* fA  = (float*)take((size_t)NV * 64 * 4);
    float* fB  = (float*)take((size_t)CAPN * 64 * 4);
    int2*  pairs1  = (int2*)take((size_t)27 * NV * 8);     // 3.46 MB, strided NV
    int2*  pairs2  = (int2*)take((size_t)3 * CAPN * 8);    // strided CAPN
    int2*  pairs34 = (int2*)take((size_t)27 * CAPN * 8);   // 6.91 MB
    int2*  pairs5  = (int2*)take((size_t)3 * CAPN * 8);

    hipMemsetAsync(ctr, 0x00, zero_len, stream);
    hipMemsetAsync(grid0, 0xFF, ff_len, stream);
    hipMemsetAsync(out, 0x00, (size_t)out_size * 4, stream);

    setup1_k<<<dim3(864, 6), 256, 0, stream>>>(coors, grid0, w1, w2, w3, w4, w5,
                                               w1t, w2t, w3t, w4t, w5t);
    setup2_k<<<2651, 256, 0, stream>>>(coors, grid0, grid1, list1, list2, ctr, pairs1);
    setup3_k<<<4125, 256, 0, stream>>>(grid0, grid1, list1, list2, ctr,
                                       pairs2, pairs34, pairs5);

    // conv1: 128->64 as two 64-ch halves sharing pair entries (54 slices)
    pconv_k<128, true, 27, NV><<<1024, 256, 0, stream>>>(vf, w1t, pairs1,
                                                         ctr + PC(2), acc1);
    bn_k<false, true><<<(NV * 64) / 256, 256, 0, stream>>>(acc1, fA, ctr,
        bg, bb, bm, bv);
    // conv2
    pconv_k<64, false, 3, CAPN><<<1024, 256, 0, stream>>>(fA, w2t, pairs2,
                                                          ctr + PC(29), accX);
    bn_k<true, false><<<(CAPN * 64) / 256, 256, 0, stream>>>(accX, fB, ctr,
        bg + 64, bb + 64, bm + 64, bv + 64);
    // conv3
    pconv_k<64, false, 27, CAPN><<<1024, 256, 0, stream>>>(fB, w3t, pairs34,
                                                           ctr + PC(32), accX);
    bn_k<true, false><<<(CAPN * 64) / 256, 256, 0, stream>>>(accX, fB, ctr,
        bg + 128, bb + 128, bm + 128, bv + 128);
    // conv4
    pconv_k<64, false, 27, CAPN><<<1024, 256, 0, stream>>>(fB, w4t, pairs34,
                                                           ctr + PC(32), accX);
    bn_k<false, false><<<(CAPN * 64) / 256, 256, 0, stream>>>(accX, fB, ctr,
        bg + 192, bb + 192, bm + 192, bv + 192);
    // conv5
    pconv_k<64, false, 3, CAPN><<<1024, 256, 0, stream>>>(fB, w5t, pairs5,
                                                          ctr + PC(59), acc5);
    bn5_k<<<CAPN / 64, 256, 0, stream>>>(acc5, list2, ctr,
        bg + 256, bb + 256, bm + 256, bv + 256, out);
}